// Round 1
// baseline (715.709 us; speedup 1.0000x reference)
//
#include <hip/hip_runtime.h>
#include <hip/hip_bf16.h>

typedef float f32x4 __attribute__((ext_vector_type(4)));
typedef __bf16 bf16x8 __attribute__((ext_vector_type(8)));
typedef __bf16 bf16x4 __attribute__((ext_vector_type(4)));

#define S_LEN 8192
#define HIDDEN 1024
#define NH 8
#define HD 128

__device__ __forceinline__ void async16(const void* g, void* l) {
  __builtin_amdgcn_global_load_lds(
      (const __attribute__((address_space(1))) char*)g,
      (__attribute__((address_space(3))) char*)l, 16, 0, 0);
}

// ---------------- fp32 -> bf16 cast ----------------
__global__ void cast_bf16_kernel(const float* __restrict__ in, __bf16* __restrict__ out) {
  int i = (blockIdx.x * blockDim.x + threadIdx.x) * 4;
  float4 v = *(const float4*)(in + i);
  bf16x4 o;
  o[0] = (__bf16)v.x; o[1] = (__bf16)v.y; o[2] = (__bf16)v.z; o[3] = (__bf16)v.w;
  *(bf16x4*)(out + i) = o;
}

// ---------------- QKV GEMM: [8192x1024] x [3072x1024]^T + bias ----------------
// Writes Q[h][s][d], K[h][s][d], Vt[h][d][s] (bf16)
__global__ __launch_bounds__(256) void gemm_qkv(
    const __bf16* __restrict__ A, const __bf16* __restrict__ W,
    const float* __restrict__ bias,
    __bf16* __restrict__ Qb, __bf16* __restrict__ Kb, __bf16* __restrict__ Vt)
{
  __shared__ __bf16 As[128 * 32];
  __shared__ __bf16 Bs[128 * 32];
  const int t = threadIdx.x;
  const int lane = t & 63;
  const int w = t >> 6;
  const int wy = w >> 1, wx = w & 1;
  const int quad = lane >> 4, l15 = lane & 15;
  const int m0 = blockIdx.y * 128;
  const int n0 = blockIdx.x * 128;
  f32x4 acc[4][4] = {};
  for (int kt = 0; kt < HIDDEN; kt += 32) {
#pragma unroll
    for (int j = 0; j < 2; ++j) {
      int idx = j * 256 + t;
      int row = idx >> 2, c8 = (idx & 3) * 8;
      async16(A + (size_t)(m0 + row) * HIDDEN + kt + c8, As + idx * 8);
      async16(W + (size_t)(n0 + row) * HIDDEN + kt + c8, Bs + idx * 8);
    }
    __syncthreads();
    bf16x8 af[4], bfr[4];
#pragma unroll
    for (int i = 0; i < 4; ++i)
      af[i] = *(const bf16x8*)(As + (wy * 64 + i * 16 + l15) * 32 + quad * 8);
#pragma unroll
    for (int i = 0; i < 4; ++i)
      bfr[i] = *(const bf16x8*)(Bs + (wx * 64 + i * 16 + l15) * 32 + quad * 8);
#pragma unroll
    for (int mt = 0; mt < 4; ++mt)
#pragma unroll
      for (int nt = 0; nt < 4; ++nt)
        acc[mt][nt] = __builtin_amdgcn_mfma_f32_16x16x32_bf16(af[mt], bfr[nt], acc[mt][nt], 0, 0, 0);
    __syncthreads();
  }
  // epilogue: bias + scatter to Q / K / Vt (region is block-uniform: N tile = 128 = one head)
  float bv[4];
  int cols[4];
#pragma unroll
  for (int nt = 0; nt < 4; ++nt) {
    cols[nt] = n0 + wx * 64 + nt * 16 + l15;
    bv[nt] = bias[cols[nt]];
  }
#pragma unroll
  for (int mt = 0; mt < 4; ++mt) {
    int srow_base = m0 + wy * 64 + mt * 16 + quad * 4;
#pragma unroll
    for (int nt = 0; nt < 4; ++nt) {
      int c = cols[nt];
#pragma unroll
      for (int r = 0; r < 4; ++r) {
        int s = srow_base + r;
        __bf16 b = (__bf16)(acc[mt][nt][r] + bv[nt]);
        if (n0 < 1024) {
          int h = c >> 7, d = c & 127;
          Qb[(size_t)h * S_LEN * HD + (size_t)s * HD + d] = b;
        } else if (n0 < 2048) {
          int c2 = c - 1024; int h = c2 >> 7, d = c2 & 127;
          Kb[(size_t)h * S_LEN * HD + (size_t)s * HD + d] = b;
        } else {
          int c2 = c - 2048; int h = c2 >> 7, d = c2 & 127;
          Vt[(size_t)h * HD * S_LEN + (size_t)d * S_LEN + s] = b;
        }
      }
    }
  }
}

// ---------------- in-place RoPE on Q, K ----------------
__global__ void rope_kernel(__bf16* __restrict__ Qb, __bf16* __restrict__ Kb,
                            const float* __restrict__ fcos, const float* __restrict__ fsin)
{
  int gid = blockIdx.x * blockDim.x + threadIdx.x;
  int d = gid & 63;
  int h = (gid >> 6) & 7;
  int s = gid >> 9;
  float c1 = fcos[s * 128 + d],      s1 = fsin[s * 128 + d];
  float c2 = fcos[s * 128 + d + 64], s2 = fsin[s * 128 + d + 64];
  size_t base = (size_t)h * S_LEN * HD + (size_t)s * HD + d;
  float q1 = (float)Qb[base], q2 = (float)Qb[base + 64];
  Qb[base]      = (__bf16)(q1 * c1 - q2 * s1);
  Qb[base + 64] = (__bf16)(q2 * c2 + q1 * s2);
  float k1 = (float)Kb[base], k2 = (float)Kb[base + 64];
  Kb[base]      = (__bf16)(k1 * c1 - k2 * s1);
  Kb[base + 64] = (__bf16)(k2 * c2 + k1 * s2);
}

// ---------------- causal flash attention ----------------
// BM=BN=64, 4 waves x 16 q-rows. XOR-chunk-swizzled LDS to kill ds_read_b128 bank conflicts.
__global__ __launch_bounds__(256) void attn_kernel(
    const __bf16* __restrict__ Qb, const __bf16* __restrict__ Kb,
    const __bf16* __restrict__ Vt, float* __restrict__ out)
{
  __shared__ __bf16 Ks[64 * 128];   // [kr][d], chunk-swizzled by kr&7
  __shared__ __bf16 Vs[128 * 64];   // [d][kr], chunk-swizzled by d&7
  __shared__ __bf16 Ps[4 * 16 * 64];// per-wave [m][k], chunk-swizzled by m&7
  const int t = threadIdx.x;
  const int lane = t & 63, w = t >> 6;
  const int quad = lane >> 4, l15 = lane & 15;
  const int h = blockIdx.y;
  const int qi = (int)gridDim.x - 1 - (int)blockIdx.x;  // longest blocks dispatch first
  const int qs = qi * 64;
  const float scale = 0.08838834764831845f;
  const __bf16* Qh = Qb + (size_t)h * S_LEN * HD;
  const __bf16* Kh = Kb + (size_t)h * S_LEN * HD;
  const __bf16* Vh = Vt + (size_t)h * HD * S_LEN;

  bf16x8 qf[4];
  int qrow = qs + w * 16 + l15;
#pragma unroll
  for (int kb = 0; kb < 4; ++kb)
    qf[kb] = *(const bf16x8*)(Qh + (size_t)qrow * HD + kb * 32 + quad * 8);

  f32x4 o[8] = {};
  float m_i[4], l_i[4];
#pragma unroll
  for (int r = 0; r < 4; ++r) { m_i[r] = -INFINITY; l_i[r] = 0.f; }
  const int sw = l15 & 7;

  for (int j = 0; j <= qi; ++j) {
    int ks0 = j * 64;
#pragma unroll
    for (int li = 0; li < 4; ++li) {        // stage K tile (64x128, 16KB)
      int slot = li * 256 + t;
      int kr = slot >> 4, cp = slot & 15;
      int csrc = cp ^ (kr & 7);
      async16(Kh + (size_t)(ks0 + kr) * HD + csrc * 8, Ks + slot * 8);
    }
#pragma unroll
    for (int li = 0; li < 4; ++li) {        // stage V^T tile (128x64, 16KB)
      int slot = li * 256 + t;
      int d = slot >> 3, cp = slot & 7;
      int csrc = cp ^ (d & 7);
      async16(Vh + (size_t)d * S_LEN + ks0 + csrc * 8, Vs + slot * 8);
    }
    __syncthreads();

    // S = Q K^T (16x64 per wave)
    f32x4 sc[4] = {};
#pragma unroll
    for (int kb = 0; kb < 4; ++kb)
#pragma unroll
      for (int nt = 0; nt < 4; ++nt) {
        bf16x8 kf = *(const bf16x8*)(Ks + (nt * 16 + l15) * 128 + (((kb * 4 + quad) ^ sw) * 8));
        sc[nt] = __builtin_amdgcn_mfma_f32_16x16x32_bf16(qf[kb], kf, sc[nt], 0, 0, 0);
      }

    // scale + causal mask (only the diagonal tile is partially masked)
    if (j == qi) {
#pragma unroll
      for (int nt = 0; nt < 4; ++nt)
#pragma unroll
        for (int r = 0; r < 4; ++r) {
          float v = sc[nt][r] * scale;
          sc[nt][r] = ((nt * 16 + l15) > (w * 16 + quad * 4 + r)) ? -1e30f : v;
        }
    } else {
#pragma unroll
      for (int nt = 0; nt < 4; ++nt)
#pragma unroll
        for (int r = 0; r < 4; ++r)
          sc[nt][r] *= scale;
    }

    // online softmax; row r lives in lanes sharing quad (xor 1,2,4,8 stays in-group)
    float al[4];
#pragma unroll
    for (int r = 0; r < 4; ++r) {
      float mx = fmaxf(fmaxf(sc[0][r], sc[1][r]), fmaxf(sc[2][r], sc[3][r]));
      mx = fmaxf(mx, __shfl_xor(mx, 1));
      mx = fmaxf(mx, __shfl_xor(mx, 2));
      mx = fmaxf(mx, __shfl_xor(mx, 4));
      mx = fmaxf(mx, __shfl_xor(mx, 8));
      float mnew = fmaxf(m_i[r], mx);
      float alpha = __expf(m_i[r] - mnew);
      float rs = 0.f;
#pragma unroll
      for (int nt = 0; nt < 4; ++nt) {
        float p = __expf(sc[nt][r] - mnew);
        sc[nt][r] = p;
        rs += p;
      }
      rs += __shfl_xor(rs, 1);
      rs += __shfl_xor(rs, 2);
      rs += __shfl_xor(rs, 4);
      rs += __shfl_xor(rs, 8);
      l_i[r] = l_i[r] * alpha + rs;
      m_i[r] = mnew;
      al[r] = alpha;
    }
#pragma unroll
    for (int ot = 0; ot < 8; ++ot)
#pragma unroll
      for (int r = 0; r < 4; ++r)
        o[ot][r] *= al[r];

    // P: C-layout -> A-layout via per-wave LDS round-trip
#pragma unroll
    for (int nt = 0; nt < 4; ++nt)
#pragma unroll
      for (int r = 0; r < 4; ++r) {
        int row = quad * 4 + r;
        int col = nt * 16 + l15;
        int cp = (col >> 3) ^ (row & 7);
        Ps[w * 1024 + row * 64 + cp * 8 + (col & 7)] = (__bf16)sc[nt][r];
      }
    __syncthreads();

    // O += P V
#pragma unroll
    for (int kb = 0; kb < 2; ++kb) {
      bf16x8 pf = *(const bf16x8*)(Ps + w * 1024 + l15 * 64 + (((kb * 4 + quad) ^ sw) * 8));
#pragma unroll
      for (int ot = 0; ot < 8; ++ot) {
        bf16x8 vf = *(const bf16x8*)(Vs + (ot * 16 + l15) * 64 + (((kb * 4 + quad) ^ sw) * 8));
        o[ot] = __builtin_amdgcn_mfma_f32_16x16x32_bf16(pf, vf, o[ot], 0, 0, 0);
      }
    }
    __syncthreads();
  }

  // epilogue: O / l -> out[s][h][d] (fp32)
#pragma unroll
  for (int r = 0; r < 4; ++r) l_i[r] = 1.0f / l_i[r];
#pragma unroll
  for (int ot = 0; ot < 8; ++ot)
#pragma unroll
    for (int r = 0; r < 4; ++r) {
      int s = qs + w * 16 + quad * 4 + r;
      out[(size_t)s * 1024 + h * 128 + ot * 16 + l15] = o[ot][r] * l_i[r];
    }
}

extern "C" void kernel_launch(void* const* d_in, const int* in_sizes, int n_in,
                              void* d_out, int out_size, void* d_ws, size_t ws_size,
                              hipStream_t stream)
{
  const float* x    = (const float*)d_in[0];   // 8192*1024
  const float* fcos = (const float*)d_in[1];   // 8192*128
  const float* fsin = (const float*)d_in[2];   // 8192*128
  const float* wq   = (const float*)d_in[3];   // 3072*1024
  const float* bias = (const float*)d_in[4];   // 3072
  float* out = (float*)d_out;

  char* ws = (char*)d_ws;
  __bf16* xb = (__bf16*)ws;                      // 16.78 MB
  __bf16* wb = (__bf16*)(ws + 16777216);         //  6.29 MB
  __bf16* Qb = (__bf16*)(ws + 23068672);         // 16.78 MB
  __bf16* Kb = (__bf16*)(ws + 39845888);         // 16.78 MB
  __bf16* Vt = (__bf16*)(ws + 56623104);         // 16.78 MB (end 73.4 MB)

  cast_bf16_kernel<<<8192, 256, 0, stream>>>(x, xb);
  cast_bf16_kernel<<<3072, 256, 0, stream>>>(wq, wb);
  dim3 gg(24, 64);
  gemm_qkv<<<gg, 256, 0, stream>>>(xb, wb, bias, Qb, Kb, Vt);
  rope_kernel<<<16384, 256, 0, stream>>>(Qb, Kb, fcos, fsin);
  dim3 ga(128, 8);
  attn_kernel<<<ga, 256, 0, stream>>>(Qb, Kb, Vt, out);
}

// Round 2
// 687.506 us; speedup vs baseline: 1.0410x; 1.0410x over previous
//
#include <hip/hip_runtime.h>
#include <hip/hip_bf16.h>

typedef float f32x4 __attribute__((ext_vector_type(4)));
typedef __bf16 bf16x8 __attribute__((ext_vector_type(8)));
typedef __bf16 bf16x4 __attribute__((ext_vector_type(4)));

#define S_LEN 8192
#define HIDDEN 1024
#define NH 8
#define HD 128

__device__ __forceinline__ void async16(const void* g, void* l) {
  __builtin_amdgcn_global_load_lds(
      (const __attribute__((address_space(1))) char*)g,
      (__attribute__((address_space(3))) char*)l, 16, 0, 0);
}

// ---------------- fp32 -> bf16 cast ----------------
__global__ void cast_bf16_kernel(const float* __restrict__ in, __bf16* __restrict__ out) {
  int i = (blockIdx.x * blockDim.x + threadIdx.x) * 4;
  float4 v = *(const float4*)(in + i);
  bf16x4 o;
  o[0] = (__bf16)v.x; o[1] = (__bf16)v.y; o[2] = (__bf16)v.z; o[3] = (__bf16)v.w;
  *(bf16x4*)(out + i) = o;
}

// ---------------- QKV GEMM: [8192x1024] x [3072x1024]^T + bias ----------------
// Writes Q[h][s][d], K[h][s][d], Vt[h][d][s] (bf16)
__global__ __launch_bounds__(256) void gemm_qkv(
    const __bf16* __restrict__ A, const __bf16* __restrict__ W,
    const float* __restrict__ bias,
    __bf16* __restrict__ Qb, __bf16* __restrict__ Kb, __bf16* __restrict__ Vt)
{
  __shared__ __bf16 As[128 * 32];
  __shared__ __bf16 Bs[128 * 32];
  const int t = threadIdx.x;
  const int lane = t & 63;
  const int w = t >> 6;
  const int wy = w >> 1, wx = w & 1;
  const int quad = lane >> 4, l15 = lane & 15;
  const int m0 = blockIdx.y * 128;
  const int n0 = blockIdx.x * 128;
  f32x4 acc[4][4] = {};
  for (int kt = 0; kt < HIDDEN; kt += 32) {
#pragma unroll
    for (int j = 0; j < 2; ++j) {
      int idx = j * 256 + t;
      int row = idx >> 2, c8 = (idx & 3) * 8;
      async16(A + (size_t)(m0 + row) * HIDDEN + kt + c8, As + idx * 8);
      async16(W + (size_t)(n0 + row) * HIDDEN + kt + c8, Bs + idx * 8);
    }
    __syncthreads();
    bf16x8 af[4], bfr[4];
#pragma unroll
    for (int i = 0; i < 4; ++i)
      af[i] = *(const bf16x8*)(As + (wy * 64 + i * 16 + l15) * 32 + quad * 8);
#pragma unroll
    for (int i = 0; i < 4; ++i)
      bfr[i] = *(const bf16x8*)(Bs + (wx * 64 + i * 16 + l15) * 32 + quad * 8);
#pragma unroll
    for (int mt = 0; mt < 4; ++mt)
#pragma unroll
      for (int nt = 0; nt < 4; ++nt)
        acc[mt][nt] = __builtin_amdgcn_mfma_f32_16x16x32_bf16(af[mt], bfr[nt], acc[mt][nt], 0, 0, 0);
    __syncthreads();
  }
  float bv[4];
  int cols[4];
#pragma unroll
  for (int nt = 0; nt < 4; ++nt) {
    cols[nt] = n0 + wx * 64 + nt * 16 + l15;
    bv[nt] = bias[cols[nt]];
  }
#pragma unroll
  for (int mt = 0; mt < 4; ++mt) {
    int srow_base = m0 + wy * 64 + mt * 16 + quad * 4;
#pragma unroll
    for (int nt = 0; nt < 4; ++nt) {
      int c = cols[nt];
#pragma unroll
      for (int r = 0; r < 4; ++r) {
        int s = srow_base + r;
        __bf16 b = (__bf16)(acc[mt][nt][r] + bv[nt]);
        if (n0 < 1024) {
          int h = c >> 7, d = c & 127;
          Qb[(size_t)h * S_LEN * HD + (size_t)s * HD + d] = b;
        } else if (n0 < 2048) {
          int c2 = c - 1024; int h = c2 >> 7, d = c2 & 127;
          Kb[(size_t)h * S_LEN * HD + (size_t)s * HD + d] = b;
        } else {
          int c2 = c - 2048; int h = c2 >> 7, d = c2 & 127;
          Vt[(size_t)h * HD * S_LEN + (size_t)d * S_LEN + s] = b;
        }
      }
    }
  }
}

// ---------------- in-place RoPE on Q (pre-scaled by 1/sqrt(D)), K ----------------
__global__ void rope_kernel(__bf16* __restrict__ Qb, __bf16* __restrict__ Kb,
                            const float* __restrict__ fcos, const float* __restrict__ fsin)
{
  const float scale = 0.08838834764831845f;
  int gid = blockIdx.x * blockDim.x + threadIdx.x;
  int d = gid & 63;
  int h = (gid >> 6) & 7;
  int s = gid >> 9;
  float c1 = fcos[s * 128 + d],      s1 = fsin[s * 128 + d];
  float c2 = fcos[s * 128 + d + 64], s2 = fsin[s * 128 + d + 64];
  size_t base = (size_t)h * S_LEN * HD + (size_t)s * HD + d;
  float q1 = (float)Qb[base], q2 = (float)Qb[base + 64];
  Qb[base]      = (__bf16)((q1 * c1 - q2 * s1) * scale);
  Qb[base + 64] = (__bf16)((q2 * c2 + q1 * s2) * scale);
  float k1 = (float)Kb[base], k2 = (float)Kb[base + 64];
  Kb[base]      = (__bf16)(k1 * c1 - k2 * s1);
  Kb[base + 64] = (__bf16)(k2 * c2 + k1 * s2);
}

// ---------------- causal flash attention v2 ----------------
// BM=128, BN=64, 4 waves x 32 q-rows (mt=2), double-buffered K/V, 1 barrier/tile.
// Block pairing: b<256 -> qi=63-(b>>3) (big, dispatched first); b>=256 -> qi=(b-256)>>3.
__global__ __launch_bounds__(256, 2) void attn_kernel(
    const __bf16* __restrict__ Qb, const __bf16* __restrict__ Kb,
    const __bf16* __restrict__ Vt, float* __restrict__ out)
{
  __shared__ __bf16 Ks[2][64 * 128];   // [kv][d], chunk-swizzled by kv&7
  __shared__ __bf16 Vs[2][128 * 64];   // [d][kv], chunk-swizzled by d&7
  __shared__ __bf16 Ps[4 * 32 * 64];   // per-wave [32 rows][64 kv], swizzled by row&7
  const int t = threadIdx.x;
  const int lane = t & 63, w = t >> 6;
  const int quad = lane >> 4, l15 = lane & 15;
  const int sw = l15 & 7;
  int b = blockIdx.x;
  int head, qi;
  if (b < 256) { head = b & 7; qi = 63 - (b >> 3); }
  else         { head = (b - 256) & 7; qi = (b - 256) >> 3; }
  const int qs = qi * 128;
  const int jmax = 2 * qi + 1;
  const int jmax_w = 2 * qi + (w >> 1);  // waves 0,1 (rows 0-63) skip the last tile
  const __bf16* Qh = Qb + (size_t)head * S_LEN * HD;
  const __bf16* Kh = Kb + (size_t)head * S_LEN * HD;
  const __bf16* Vh = Vt + (size_t)head * HD * S_LEN;

  // Q fragments (Q pre-scaled in rope_kernel)
  bf16x8 qf[2][4];
#pragma unroll
  for (int mt = 0; mt < 2; ++mt) {
    int qrow = qs + w * 32 + mt * 16 + l15;
#pragma unroll
    for (int kb = 0; kb < 4; ++kb)
      qf[mt][kb] = *(const bf16x8*)(Qh + (size_t)qrow * HD + kb * 32 + quad * 8);
  }

  f32x4 o[2][8] = {};
  float m_i[2][4], l_i[2][4];
#pragma unroll
  for (int mt = 0; mt < 2; ++mt)
#pragma unroll
    for (int r = 0; r < 4; ++r) { m_i[mt][r] = -INFINITY; l_i[mt][r] = 0.f; }

  // stage tile j into buffer sel
  auto stage = [&](int j, int sel) {
    const __bf16* Kp = Kh + (size_t)(j * 64) * HD;
    __bf16* Kd = &Ks[sel][0];
#pragma unroll
    for (int li = 0; li < 4; ++li) {
      int slot = li * 256 + t;
      int kr = slot >> 4, cp = slot & 15;
      async16(Kp + (size_t)kr * HD + (cp ^ (kr & 7)) * 8, Kd + slot * 8);
    }
    const __bf16* Vp = Vh + j * 64;
    __bf16* Vd = &Vs[sel][0];
#pragma unroll
    for (int li = 0; li < 4; ++li) {
      int slot = li * 256 + t;
      int d = slot >> 3, cp = slot & 7;
      async16(Vp + (size_t)d * S_LEN + (cp ^ (d & 7)) * 8, Vd + slot * 8);
    }
  };

  stage(0, 0);

  for (int j = 0; j <= jmax; ++j) {
    __syncthreads();             // drains prefetch for buf[j&1]; frees buf[(j+1)&1]
    const int cur = j & 1;
    if (j < jmax) stage(j + 1, cur ^ 1);   // fly during this tile's compute
    if (j > jmax_w) continue;              // fully-masked tile for this wave
    const __bf16* Ksb = &Ks[cur][0];
    const __bf16* Vsb = &Vs[cur][0];
    const int ks0 = j * 64;

    // S = Q K^T : 2 x (16x64) per wave, K-frag reused across mt
    f32x4 sc[2][4] = {};
#pragma unroll
    for (int kb = 0; kb < 4; ++kb)
#pragma unroll
      for (int nt = 0; nt < 4; ++nt) {
        bf16x8 kf = *(const bf16x8*)(Ksb + (nt * 16 + l15) * 128 + (((kb * 4 + quad) ^ sw) * 8));
        sc[0][nt] = __builtin_amdgcn_mfma_f32_16x16x32_bf16(qf[0][kb], kf, sc[0][nt], 0, 0, 0);
        sc[1][nt] = __builtin_amdgcn_mfma_f32_16x16x32_bf16(qf[1][kb], kf, sc[1][nt], 0, 0, 0);
      }

    // causal mask (only the two diagonal tiles)
    if (j >= 2 * qi) {
#pragma unroll
      for (int mt = 0; mt < 2; ++mt)
#pragma unroll
        for (int nt = 0; nt < 4; ++nt)
#pragma unroll
          for (int r = 0; r < 4; ++r)
            if (ks0 + nt * 16 + l15 > qs + w * 32 + mt * 16 + quad * 4 + r)
              sc[mt][nt][r] = -1e30f;
    }

    // online softmax (row's 64 scores live across 16 lanes l15 x 4 nt)
    float al[2][4];
#pragma unroll
    for (int mt = 0; mt < 2; ++mt)
#pragma unroll
      for (int r = 0; r < 4; ++r) {
        float mx = fmaxf(fmaxf(sc[mt][0][r], sc[mt][1][r]), fmaxf(sc[mt][2][r], sc[mt][3][r]));
        mx = fmaxf(mx, __shfl_xor(mx, 1));
        mx = fmaxf(mx, __shfl_xor(mx, 2));
        mx = fmaxf(mx, __shfl_xor(mx, 4));
        mx = fmaxf(mx, __shfl_xor(mx, 8));
        float mnew = fmaxf(m_i[mt][r], mx);
        float alpha = __expf(m_i[mt][r] - mnew);
        float rs = 0.f;
#pragma unroll
        for (int nt = 0; nt < 4; ++nt) {
          float p = __expf(sc[mt][nt][r] - mnew);
          sc[mt][nt][r] = p;
          rs += p;
        }
        rs += __shfl_xor(rs, 1);
        rs += __shfl_xor(rs, 2);
        rs += __shfl_xor(rs, 4);
        rs += __shfl_xor(rs, 8);
        l_i[mt][r] = l_i[mt][r] * alpha + rs;
        m_i[mt][r] = mnew;
        al[mt][r] = alpha;
      }
#pragma unroll
    for (int mt = 0; mt < 2; ++mt)
#pragma unroll
      for (int ot = 0; ot < 8; ++ot)
#pragma unroll
        for (int r = 0; r < 4; ++r)
          o[mt][ot][r] *= al[mt][r];

    // P: C-layout -> A-layout via per-wave LDS (same-wave DS ops are in-order; no barrier)
#pragma unroll
    for (int mt = 0; mt < 2; ++mt)
#pragma unroll
      for (int nt = 0; nt < 4; ++nt)
#pragma unroll
        for (int r = 0; r < 4; ++r) {
          int row = mt * 16 + quad * 4 + r;
          int col = nt * 16 + l15;
          int cp = (col >> 3) ^ (row & 7);
          Ps[w * 2048 + row * 64 + cp * 8 + (col & 7)] = (__bf16)sc[mt][nt][r];
        }

    // O += P V, V-frag reused across mt
#pragma unroll
    for (int kb = 0; kb < 2; ++kb) {
      bf16x8 pf0 = *(const bf16x8*)(Ps + w * 2048 + l15 * 64 + (((kb * 4 + quad) ^ sw) * 8));
      bf16x8 pf1 = *(const bf16x8*)(Ps + w * 2048 + (16 + l15) * 64 + (((kb * 4 + quad) ^ sw) * 8));
#pragma unroll
      for (int ot = 0; ot < 8; ++ot) {
        bf16x8 vf = *(const bf16x8*)(Vsb + (ot * 16 + l15) * 64 + (((kb * 4 + quad) ^ sw) * 8));
        o[0][ot] = __builtin_amdgcn_mfma_f32_16x16x32_bf16(pf0, vf, o[0][ot], 0, 0, 0);
        o[1][ot] = __builtin_amdgcn_mfma_f32_16x16x32_bf16(pf1, vf, o[1][ot], 0, 0, 0);
      }
    }
  }

  // epilogue
#pragma unroll
  for (int mt = 0; mt < 2; ++mt)
#pragma unroll
    for (int r = 0; r < 4; ++r) l_i[mt][r] = 1.0f / l_i[mt][r];
#pragma unroll
  for (int mt = 0; mt < 2; ++mt)
#pragma unroll
    for (int ot = 0; ot < 8; ++ot)
#pragma unroll
      for (int r = 0; r < 4; ++r) {
        int s = qs + w * 32 + mt * 16 + quad * 4 + r;
        out[(size_t)s * 1024 + head * 128 + ot * 16 + l15] = o[mt][ot][r] * l_i[mt][r];
      }
}

extern "C" void kernel_launch(void* const* d_in, const int* in_sizes, int n_in,
                              void* d_out, int out_size, void* d_ws, size_t ws_size,
                              hipStream_t stream)
{
  const float* x    = (const float*)d_in[0];   // 8192*1024
  const float* fcos = (const float*)d_in[1];   // 8192*128
  const float* fsin = (const float*)d_in[2];   // 8192*128
  const float* wq   = (const float*)d_in[3];   // 3072*1024
  const float* bias = (const float*)d_in[4];   // 3072
  float* out = (float*)d_out;

  char* ws = (char*)d_ws;
  __bf16* xb = (__bf16*)ws;                      // 16.78 MB
  __bf16* wb = (__bf16*)(ws + 16777216);         //  6.29 MB
  __bf16* Qb = (__bf16*)(ws + 23068672);         // 16.78 MB
  __bf16* Kb = (__bf16*)(ws + 39845888);         // 16.78 MB
  __bf16* Vt = (__bf16*)(ws + 56623104);         // 16.78 MB (end 73.4 MB)

  cast_bf16_kernel<<<8192, 256, 0, stream>>>(x, xb);
  cast_bf16_kernel<<<3072, 256, 0, stream>>>(wq, wb);
  dim3 gg(24, 64);
  gemm_qkv<<<gg, 256, 0, stream>>>(xb, wb, bias, Qb, Kb, Vt);
  rope_kernel<<<16384, 256, 0, stream>>>(Qb, Kb, fcos, fsin);
  attn_kernel<<<512, 256, 0, stream>>>(Qb, Kb, Vt, out);
}

// Round 3
// 582.065 us; speedup vs baseline: 1.2296x; 1.1811x over previous
//
#include <hip/hip_runtime.h>
#include <hip/hip_bf16.h>

typedef float f32x4 __attribute__((ext_vector_type(4)));
typedef __bf16 bf16x8 __attribute__((ext_vector_type(8)));
typedef __bf16 bf16x4 __attribute__((ext_vector_type(4)));

#define S_LEN 8192
#define HIDDEN 1024
#define NH 8
#define HD 128

__device__ __forceinline__ void async16(const void* g, void* l) {
  __builtin_amdgcn_global_load_lds(
      (const __attribute__((address_space(1))) char*)g,
      (__attribute__((address_space(3))) char*)l, 16, 0, 0);
}

// ---------------- fp32 -> bf16 cast ----------------
__global__ void cast_bf16_kernel(const float* __restrict__ in, __bf16* __restrict__ out) {
  int i = (blockIdx.x * blockDim.x + threadIdx.x) * 4;
  float4 v = *(const float4*)(in + i);
  bf16x4 o;
  o[0] = (__bf16)v.x; o[1] = (__bf16)v.y; o[2] = (__bf16)v.z; o[3] = (__bf16)v.w;
  *(bf16x4*)(out + i) = o;
}

// ---------------- QKV GEMM: [8192x1024] x [3072x1024]^T + bias ----------------
__global__ __launch_bounds__(256) void gemm_qkv(
    const __bf16* __restrict__ A, const __bf16* __restrict__ W,
    const float* __restrict__ bias,
    __bf16* __restrict__ Qb, __bf16* __restrict__ Kb, __bf16* __restrict__ Vt)
{
  __shared__ __bf16 As[128 * 32];
  __shared__ __bf16 Bs[128 * 32];
  const int t = threadIdx.x;
  const int lane = t & 63;
  const int w = t >> 6;
  const int wy = w >> 1, wx = w & 1;
  const int quad = lane >> 4, l15 = lane & 15;
  const int m0 = blockIdx.y * 128;
  const int n0 = blockIdx.x * 128;
  f32x4 acc[4][4] = {};
  for (int kt = 0; kt < HIDDEN; kt += 32) {
#pragma unroll
    for (int j = 0; j < 2; ++j) {
      int idx = j * 256 + t;
      int row = idx >> 2, c8 = (idx & 3) * 8;
      async16(A + (size_t)(m0 + row) * HIDDEN + kt + c8, As + idx * 8);
      async16(W + (size_t)(n0 + row) * HIDDEN + kt + c8, Bs + idx * 8);
    }
    __syncthreads();
    bf16x8 af[4], bfr[4];
#pragma unroll
    for (int i = 0; i < 4; ++i)
      af[i] = *(const bf16x8*)(As + (wy * 64 + i * 16 + l15) * 32 + quad * 8);
#pragma unroll
    for (int i = 0; i < 4; ++i)
      bfr[i] = *(const bf16x8*)(Bs + (wx * 64 + i * 16 + l15) * 32 + quad * 8);
#pragma unroll
    for (int mt = 0; mt < 4; ++mt)
#pragma unroll
      for (int nt = 0; nt < 4; ++nt)
        acc[mt][nt] = __builtin_amdgcn_mfma_f32_16x16x32_bf16(af[mt], bfr[nt], acc[mt][nt], 0, 0, 0);
    __syncthreads();
  }
  float bv[4];
  int cols[4];
#pragma unroll
  for (int nt = 0; nt < 4; ++nt) {
    cols[nt] = n0 + wx * 64 + nt * 16 + l15;
    bv[nt] = bias[cols[nt]];
  }
#pragma unroll
  for (int mt = 0; mt < 4; ++mt) {
    int srow_base = m0 + wy * 64 + mt * 16 + quad * 4;
#pragma unroll
    for (int nt = 0; nt < 4; ++nt) {
      int c = cols[nt];
#pragma unroll
      for (int r = 0; r < 4; ++r) {
        int s = srow_base + r;
        __bf16 b = (__bf16)(acc[mt][nt][r] + bv[nt]);
        if (n0 < 1024) {
          int h = c >> 7, d = c & 127;
          Qb[(size_t)h * S_LEN * HD + (size_t)s * HD + d] = b;
        } else if (n0 < 2048) {
          int c2 = c - 1024; int h = c2 >> 7, d = c2 & 127;
          Kb[(size_t)h * S_LEN * HD + (size_t)s * HD + d] = b;
        } else {
          int c2 = c - 2048; int h = c2 >> 7, d = c2 & 127;
          Vt[(size_t)h * HD * S_LEN + (size_t)d * S_LEN + s] = b;
        }
      }
    }
  }
}

// ---------------- in-place RoPE on Q (pre-scaled by 1/sqrt(D)), K ----------------
__global__ void rope_kernel(__bf16* __restrict__ Qb, __bf16* __restrict__ Kb,
                            const float* __restrict__ fcos, const float* __restrict__ fsin)
{
  const float scale = 0.08838834764831845f;
  int gid = blockIdx.x * blockDim.x + threadIdx.x;
  int d = gid & 63;
  int h = (gid >> 6) & 7;
  int s = gid >> 9;
  float c1 = fcos[s * 128 + d],      s1 = fsin[s * 128 + d];
  float c2 = fcos[s * 128 + d + 64], s2 = fsin[s * 128 + d + 64];
  size_t base = (size_t)h * S_LEN * HD + (size_t)s * HD + d;
  float q1 = (float)Qb[base], q2 = (float)Qb[base + 64];
  Qb[base]      = (__bf16)((q1 * c1 - q2 * s1) * scale);
  Qb[base + 64] = (__bf16)((q2 * c2 + q1 * s2) * scale);
  float k1 = (float)Kb[base], k2 = (float)Kb[base + 64];
  Kb[base]      = (__bf16)(k1 * c1 - k2 * s1);
  Kb[base + 64] = (__bf16)(k2 * c2 + k1 * s2);
}

// ---------------- causal flash attention v3: split-KV balanced ----------------
// 768 blocks. id -> k=id/24, r=id%24.
//   r<16 : half-row unit: qi=63-k (>=32), piece=r>>3, head=r&7, j in [p*(qi+1),(p+1)*(qi+1))
//   r>=16: full-row unit: qi=31-k (<32),  head=r-16,           j in [0, 2qi+2)
// Half-row units write normalized partials (O/l bf16, m/l fp32); merge_kernel combines.
__global__ __launch_bounds__(256, 2) void attn_kernel(
    const __bf16* __restrict__ Qb, const __bf16* __restrict__ Kb,
    const __bf16* __restrict__ Vt, float* __restrict__ out,
    __bf16* __restrict__ partO, float* __restrict__ partML)
{
  __shared__ __bf16 Ks[2][64 * 128];   // [kv][d], chunk-swizzled by kv&7
  __shared__ __bf16 Vs[2][128 * 64];   // [d][kv], chunk-swizzled by d&7
  __shared__ __bf16 Ps[4 * 32 * 64];   // per-wave [32 rows][64 kv], swizzled by row&7
  const int t = threadIdx.x;
  const int lane = t & 63, w = t >> 6;
  const int quad = lane >> 4, l15 = lane & 15;
  const int sw = l15 & 7;

  const int id = blockIdx.x;
  const int k = id / 24, r = id % 24;
  int head, qi, piece, j0, j1;
  bool isPartial;
  if (r < 16) { qi = 63 - k; piece = r >> 3; head = r & 7;
                j0 = piece * (qi + 1); j1 = j0 + (qi + 1); isPartial = true; }
  else        { qi = 31 - k; piece = 0; head = r - 16;
                j0 = 0; j1 = 2 * qi + 2; isPartial = false; }
  const int qs = qi * 128;
  const int jmax_w = 2 * qi + (w >> 1);  // beyond this tile, this wave is fully masked
  const __bf16* Qh = Qb + (size_t)head * S_LEN * HD;
  const __bf16* Kh = Kb + (size_t)head * S_LEN * HD;
  const __bf16* Vh = Vt + (size_t)head * HD * S_LEN;

  bf16x8 qf[2][4];
#pragma unroll
  for (int mt = 0; mt < 2; ++mt) {
    int qrow = qs + w * 32 + mt * 16 + l15;
#pragma unroll
    for (int kb = 0; kb < 4; ++kb)
      qf[mt][kb] = *(const bf16x8*)(Qh + (size_t)qrow * HD + kb * 32 + quad * 8);
  }

  f32x4 o[2][8] = {};
  float m_i[2][4], l_i[2][4];
#pragma unroll
  for (int mt = 0; mt < 2; ++mt)
#pragma unroll
    for (int r2 = 0; r2 < 4; ++r2) { m_i[mt][r2] = -INFINITY; l_i[mt][r2] = 0.f; }

  auto stage = [&](int j, int sel) {
    const __bf16* Kp = Kh + (size_t)(j * 64) * HD;
    __bf16* Kd = &Ks[sel][0];
#pragma unroll
    for (int li = 0; li < 4; ++li) {
      int slot = li * 256 + t;
      int kr = slot >> 4, cp = slot & 15;
      async16(Kp + (size_t)kr * HD + (cp ^ (kr & 7)) * 8, Kd + slot * 8);
    }
    const __bf16* Vp = Vh + j * 64;
    __bf16* Vd = &Vs[sel][0];
#pragma unroll
    for (int li = 0; li < 4; ++li) {
      int slot = li * 256 + t;
      int d = slot >> 3, cp = slot & 7;
      async16(Vp + (size_t)d * S_LEN + (cp ^ (d & 7)) * 8, Vd + slot * 8);
    }
  };

  stage(j0, 0);

  for (int j = j0; j < j1; ++j) {
    __syncthreads();
    const int cur = (j - j0) & 1;
    if (j + 1 < j1) stage(j + 1, cur ^ 1);
    if (j > jmax_w) continue;
    const __bf16* Ksb = &Ks[cur][0];
    const __bf16* Vsb = &Vs[cur][0];
    const int ks0 = j * 64;

    f32x4 sc[2][4] = {};
#pragma unroll
    for (int kb = 0; kb < 4; ++kb)
#pragma unroll
      for (int nt = 0; nt < 4; ++nt) {
        bf16x8 kf = *(const bf16x8*)(Ksb + (nt * 16 + l15) * 128 + (((kb * 4 + quad) ^ sw) * 8));
        sc[0][nt] = __builtin_amdgcn_mfma_f32_16x16x32_bf16(qf[0][kb], kf, sc[0][nt], 0, 0, 0);
        sc[1][nt] = __builtin_amdgcn_mfma_f32_16x16x32_bf16(qf[1][kb], kf, sc[1][nt], 0, 0, 0);
      }

    if (j >= 2 * qi) {  // only the two diagonal tiles mask
#pragma unroll
      for (int mt = 0; mt < 2; ++mt)
#pragma unroll
        for (int nt = 0; nt < 4; ++nt)
#pragma unroll
          for (int r2 = 0; r2 < 4; ++r2)
            if (ks0 + nt * 16 + l15 > qs + w * 32 + mt * 16 + quad * 4 + r2)
              sc[mt][nt][r2] = -1e30f;
    }

    float al[2][4];
#pragma unroll
    for (int mt = 0; mt < 2; ++mt)
#pragma unroll
      for (int r2 = 0; r2 < 4; ++r2) {
        float mx = fmaxf(fmaxf(sc[mt][0][r2], sc[mt][1][r2]), fmaxf(sc[mt][2][r2], sc[mt][3][r2]));
        mx = fmaxf(mx, __shfl_xor(mx, 1));
        mx = fmaxf(mx, __shfl_xor(mx, 2));
        mx = fmaxf(mx, __shfl_xor(mx, 4));
        mx = fmaxf(mx, __shfl_xor(mx, 8));
        float mnew = fmaxf(m_i[mt][r2], mx);
        float alpha = __expf(m_i[mt][r2] - mnew);
        float rs = 0.f;
#pragma unroll
        for (int nt = 0; nt < 4; ++nt) {
          float p = __expf(sc[mt][nt][r2] - mnew);
          sc[mt][nt][r2] = p;
          rs += p;
        }
        rs += __shfl_xor(rs, 1);
        rs += __shfl_xor(rs, 2);
        rs += __shfl_xor(rs, 4);
        rs += __shfl_xor(rs, 8);
        l_i[mt][r2] = l_i[mt][r2] * alpha + rs;
        m_i[mt][r2] = mnew;
        al[mt][r2] = alpha;
      }
#pragma unroll
    for (int mt = 0; mt < 2; ++mt)
#pragma unroll
      for (int ot = 0; ot < 8; ++ot)
#pragma unroll
        for (int r2 = 0; r2 < 4; ++r2)
          o[mt][ot][r2] *= al[mt][r2];

    // P: C-layout -> A-layout via per-wave LDS (same-wave DS in-order; no barrier)
#pragma unroll
    for (int mt = 0; mt < 2; ++mt)
#pragma unroll
      for (int nt = 0; nt < 4; ++nt)
#pragma unroll
        for (int r2 = 0; r2 < 4; ++r2) {
          int row = mt * 16 + quad * 4 + r2;
          int col = nt * 16 + l15;
          int cp = (col >> 3) ^ (row & 7);
          Ps[w * 2048 + row * 64 + cp * 8 + (col & 7)] = (__bf16)sc[mt][nt][r2];
        }

#pragma unroll
    for (int kb = 0; kb < 2; ++kb) {
      bf16x8 pf0 = *(const bf16x8*)(Ps + w * 2048 + l15 * 64 + (((kb * 4 + quad) ^ sw) * 8));
      bf16x8 pf1 = *(const bf16x8*)(Ps + w * 2048 + (16 + l15) * 64 + (((kb * 4 + quad) ^ sw) * 8));
#pragma unroll
      for (int ot = 0; ot < 8; ++ot) {
        bf16x8 vf = *(const bf16x8*)(Vsb + (ot * 16 + l15) * 64 + (((kb * 4 + quad) ^ sw) * 8));
        o[0][ot] = __builtin_amdgcn_mfma_f32_16x16x32_bf16(pf0, vf, o[0][ot], 0, 0, 0);
        o[1][ot] = __builtin_amdgcn_mfma_f32_16x16x32_bf16(pf1, vf, o[1][ot], 0, 0, 0);
      }
    }
  }

  // epilogue
#pragma unroll
  for (int mt = 0; mt < 2; ++mt)
#pragma unroll
    for (int r2 = 0; r2 < 4; ++r2) l_i[mt][r2] = 1.0f / l_i[mt][r2];

  if (!isPartial) {
#pragma unroll
    for (int mt = 0; mt < 2; ++mt)
#pragma unroll
      for (int ot = 0; ot < 8; ++ot)
#pragma unroll
        for (int r2 = 0; r2 < 4; ++r2) {
          int s = qs + w * 32 + mt * 16 + quad * 4 + r2;
          out[(size_t)s * 1024 + head * 128 + ot * 16 + l15] = o[mt][ot][r2] * l_i[mt][r2];
        }
  } else {
    int u = (qi - 32) * 16 + piece * 8 + head;
    __bf16* Op = partO + (size_t)u * 128 * 128;
    float* mlp = partML + u * 256;
#pragma unroll
    for (int mt = 0; mt < 2; ++mt)
#pragma unroll
      for (int ot = 0; ot < 8; ++ot)
#pragma unroll
        for (int r2 = 0; r2 < 4; ++r2) {
          int row = w * 32 + mt * 16 + quad * 4 + r2;
          Op[row * 128 + ot * 16 + l15] = (__bf16)(o[mt][ot][r2] * l_i[mt][r2]);
        }
    if (l15 == 0) {
#pragma unroll
      for (int mt = 0; mt < 2; ++mt)
#pragma unroll
        for (int r2 = 0; r2 < 4; ++r2) {
          int row = w * 32 + mt * 16 + quad * 4 + r2;
          mlp[row] = m_i[mt][r2];
          mlp[128 + row] = 1.0f / l_i[mt][r2];  // stored as l (we inverted above)
        }
    }
  }
}

// ---------------- merge split-KV partials ----------------
__global__ __launch_bounds__(256) void merge_kernel(
    const __bf16* __restrict__ partO, const float* __restrict__ partML,
    float* __restrict__ out)
{
  int b = blockIdx.x;             // 256 = 32 qi x 8 heads
  int qi = 32 + (b >> 3), head = b & 7;
  int u0 = (qi - 32) * 16 + head; // piece 0
  int u1 = u0 + 8;                // piece 1
  int t = threadIdx.x;
  int q = t >> 1, dh = (t & 1) * 64;
  float m0 = partML[u0 * 256 + q], l0 = partML[u0 * 256 + 128 + q];
  float m1 = partML[u1 * 256 + q], l1 = partML[u1 * 256 + 128 + q];
  float m = fmaxf(m0, m1);
  float w0 = __expf(m0 - m) * l0;
  float w1 = __expf(m1 - m) * l1;
  float inv = 1.0f / (w0 + w1);
  w0 *= inv; w1 *= inv;
  const __bf16* O0 = partO + ((size_t)u0 * 128 + q) * 128 + dh;
  const __bf16* O1 = partO + ((size_t)u1 * 128 + q) * 128 + dh;
  float* op = out + (size_t)(qi * 128 + q) * 1024 + head * 128 + dh;
#pragma unroll
  for (int d = 0; d < 64; d += 8) {
    bf16x8 a = *(const bf16x8*)(O0 + d);
    bf16x8 c = *(const bf16x8*)(O1 + d);
    float4 r0, r1;
    r0.x = w0 * (float)a[0] + w1 * (float)c[0];
    r0.y = w0 * (float)a[1] + w1 * (float)c[1];
    r0.z = w0 * (float)a[2] + w1 * (float)c[2];
    r0.w = w0 * (float)a[3] + w1 * (float)c[3];
    r1.x = w0 * (float)a[4] + w1 * (float)c[4];
    r1.y = w0 * (float)a[5] + w1 * (float)c[5];
    r1.z = w0 * (float)a[6] + w1 * (float)c[6];
    r1.w = w0 * (float)a[7] + w1 * (float)c[7];
    *(float4*)(op + d) = r0;
    *(float4*)(op + d + 4) = r1;
  }
}

extern "C" void kernel_launch(void* const* d_in, const int* in_sizes, int n_in,
                              void* d_out, int out_size, void* d_ws, size_t ws_size,
                              hipStream_t stream)
{
  const float* x    = (const float*)d_in[0];
  const float* fcos = (const float*)d_in[1];
  const float* fsin = (const float*)d_in[2];
  const float* wq   = (const float*)d_in[3];
  const float* bias = (const float*)d_in[4];
  float* out = (float*)d_out;

  char* ws = (char*)d_ws;
  __bf16* xb = (__bf16*)ws;                      // 16.78 MB (reused as partO by attn)
  __bf16* wb = (__bf16*)(ws + 16777216);         //  6.29 MB (reused as partML)
  __bf16* Qb = (__bf16*)(ws + 23068672);
  __bf16* Kb = (__bf16*)(ws + 39845888);
  __bf16* Vt = (__bf16*)(ws + 56623104);         // end 73.4 MB

  __bf16* partO = xb;           // 512 units x 128 x 128 bf16 = 16.78 MB (exact fit)
  float* partML = (float*)wb;   // 512 units x 256 f32 = 0.52 MB

  cast_bf16_kernel<<<8192, 256, 0, stream>>>(x, xb);
  cast_bf16_kernel<<<3072, 256, 0, stream>>>(wq, wb);
  dim3 gg(24, 64);
  gemm_qkv<<<gg, 256, 0, stream>>>(xb, wb, bias, Qb, Kb, Vt);
  rope_kernel<<<16384, 256, 0, stream>>>(Qb, Kb, fcos, fsin);
  attn_kernel<<<768, 256, 0, stream>>>(Qb, Kb, Vt, out, partO, partML);
  merge_kernel<<<256, 256, 0, stream>>>(partO, partML, out);
}